// Round 1
// baseline (309.625 us; speedup 1.0000x reference)
//
#include <hip/hip_runtime.h>

typedef unsigned short u16;
typedef u16 u16x8 __attribute__((ext_vector_type(8)));
typedef __bf16 bf16x8 __attribute__((ext_vector_type(8)));
typedef float f32x4 __attribute__((ext_vector_type(4)));

#define EMB 1024
#define TT 2048
#define BB 2
#define NHEADS 16
#define HD 64
#define MTOT (BB * TT)  // 4096

// ---------- helpers ----------
__device__ __forceinline__ u16 f2bf(float f) {
  unsigned u = __builtin_bit_cast(unsigned, f);
  u += 0x7fffu + ((u >> 16) & 1u);
  return (u16)(u >> 16);
}

__device__ __forceinline__ bf16x8 asbf(u16x8 v) {
  return __builtin_bit_cast(bf16x8, v);
}

__device__ __forceinline__ void gload16(const void* g, void* l) {
  __builtin_amdgcn_global_load_lds(
      (const __attribute__((address_space(1))) void*)g,
      (__attribute__((address_space(3))) void*)l, 16, 0, 0);
}

// ---------- conversion kernels ----------
__global__ __launch_bounds__(256) void k_conv_x(const float* __restrict__ x,
                                                u16* __restrict__ xb) {
  int i = blockIdx.x * 256 + threadIdx.x;  // 8 elems per thread
  float4 a = ((const float4*)x)[i * 2];
  float4 b = ((const float4*)x)[i * 2 + 1];
  u16x8 o;
  o[0] = f2bf(a.x); o[1] = f2bf(a.y); o[2] = f2bf(a.z); o[3] = f2bf(a.w);
  o[4] = f2bf(b.x); o[5] = f2bf(b.y); o[6] = f2bf(b.z); o[7] = f2bf(b.w);
  ((u16x8*)xb)[i] = o;
}

// W[k][n] fp32 -> Wt[n][k] bf16 (LDS-tiled transpose)
__global__ __launch_bounds__(256) void k_conv_wT(const float* __restrict__ W,
                                                 u16* __restrict__ Wt) {
  __shared__ float tile[32][33];
  int bx = blockIdx.x * 32, by = blockIdx.y * 32;
  int tx = threadIdx.x & 31;
  int ty = threadIdx.x >> 5;  // 0..7
#pragma unroll
  for (int r = ty; r < 32; r += 8) tile[r][tx] = W[(by + r) * EMB + bx + tx];
  __syncthreads();
#pragma unroll
  for (int r = ty; r < 32; r += 8)
    Wt[(bx + r) * EMB + by + tx] = f2bf(tile[tx][r]);
}

// ---------- fused QKV GEMM ----------
// A = xb [4096][1024] bf16, Bt = Wt [1024][1024] bf16 (row n, col k).
// 128x128 tile, BK=32, 4 waves each computing 64x64 (4x4 mfma 16x16x32).
__global__ __launch_bounds__(256) void k_gemm_qkv(
    const u16* __restrict__ xb, const u16* __restrict__ WqT,
    const u16* __restrict__ WkT, const u16* __restrict__ WvT,
    const float* __restrict__ bq, const float* __restrict__ bk,
    const float* __restrict__ bv, u16* __restrict__ Q, u16* __restrict__ K,
    u16* __restrict__ Vt) {
  __shared__ u16 Al[128 * 32];
  __shared__ u16 Bl[128 * 32];
  const int tid = threadIdx.x;
  const int lane = tid & 63;
  const int w = tid >> 6;
  const int wr = w >> 1, wc = w & 1;
  const int lr = lane & 15, lg = lane >> 4;
  const int m0 = blockIdx.x * 128;
  const int nb = blockIdx.y;           // 0..23
  const int seg = nb >> 3;             // 0=Q 1=K 2=V
  const int n0 = (nb & 7) * 128;
  const u16* __restrict__ Bt = (seg == 0) ? WqT : (seg == 1) ? WkT : WvT;
  const float* __restrict__ bias = (seg == 0) ? bq : (seg == 1) ? bk : bv;

  f32x4 acc[4][4];
#pragma unroll
  for (int i = 0; i < 4; i++)
#pragma unroll
    for (int j = 0; j < 4; j++) acc[i][j] = (f32x4){0.f, 0.f, 0.f, 0.f};

  const int srow = tid >> 2;           // 0..63
  const int scol = (tid & 3) * 8;
  const u16* ga0 = xb + (m0 + srow) * EMB + scol;
  const u16* gb0 = Bt + (n0 + srow) * EMB + scol;
  char* la0 = (char*)Al + w * 1024;    // wave-uniform LDS base
  char* lb0 = (char*)Bl + w * 1024;

  for (int k0 = 0; k0 < EMB; k0 += 32) {
    gload16(ga0 + k0, la0);
    gload16(ga0 + 64 * EMB + k0, la0 + 4096);
    gload16(gb0 + k0, lb0);
    gload16(gb0 + 64 * EMB + k0, lb0 + 4096);
    __syncthreads();
    u16x8 af[4], bfr[4];
#pragma unroll
    for (int mi = 0; mi < 4; mi++)
      af[mi] = *(const u16x8*)&Al[(wr * 64 + mi * 16 + lr) * 32 + lg * 8];
#pragma unroll
    for (int ni = 0; ni < 4; ni++)
      bfr[ni] = *(const u16x8*)&Bl[(wc * 64 + ni * 16 + lr) * 32 + lg * 8];
#pragma unroll
    for (int mi = 0; mi < 4; mi++)
#pragma unroll
      for (int ni = 0; ni < 4; ni++)
        acc[mi][ni] = __builtin_amdgcn_mfma_f32_16x16x32_bf16(
            asbf(af[mi]), asbf(bfr[ni]), acc[mi][ni], 0, 0, 0);
    __syncthreads();
  }

  // epilogue: bias, Q-scale, scatter to [B][H][T][D] (or Vt [B][H][D][T])
#pragma unroll
  for (int mi = 0; mi < 4; mi++) {
    const int lmb = wr * 64 + mi * 16 + lg * 4;
#pragma unroll
    for (int ni = 0; ni < 4; ni++) {
      const int ln = wc * 64 + ni * 16 + lr;
      const int n = n0 + ln;
      const float bv_ = bias[n];
      const int h = n >> 6, d = n & 63;
#pragma unroll
      for (int r = 0; r < 4; r++) {
        const int m = m0 + lmb + r;
        const int b = m >> 11, t = m & 2047;
        float v = acc[mi][ni][r] + bv_;
        if (seg == 0) {
          v *= 0.125f;  // fold 1/sqrt(D) into Q (exact pow2)
          Q[(((b * NHEADS + h) * TT) + t) * HD + d] = f2bf(v);
        } else if (seg == 1) {
          K[(((b * NHEADS + h) * TT) + t) * HD + d] = f2bf(v);
        } else {
          Vt[(((b * NHEADS + h) * HD) + d) * TT + t] = f2bf(v);
        }
      }
    }
  }
}

// ---------- causal flash attention ----------
// grid: 32 (b*h) * 32 (q-blocks of 64) = 1024 blocks; 4 waves, each owns a
// 16-row q-tile. K-tiles of 32, K/V straight from global (L2-resident).
__global__ __launch_bounds__(256) void k_attn(const u16* __restrict__ Q,
                                              const u16* __restrict__ Kg,
                                              const u16* __restrict__ Vt,
                                              u16* __restrict__ AO) {
  __shared__ u16 Plds[4][16][32];
  const int tid = threadIdx.x;
  const int lane = tid & 63;
  const int w = tid >> 6;
  const int lr = lane & 15, lg = lane >> 4;
  const int bh = blockIdx.x >> 5;             // 0..31
  const int q0 = (blockIdx.x & 31) * 64 + w * 16;
  const u16* __restrict__ Qh = Q + bh * TT * HD;
  const u16* __restrict__ Kh = Kg + bh * TT * HD;
  const u16* __restrict__ Vh = Vt + bh * HD * TT;

  u16x8 qf[2];
  qf[0] = *(const u16x8*)&Qh[(q0 + lr) * HD + lg * 8];
  qf[1] = *(const u16x8*)&Qh[(q0 + lr) * HD + 32 + lg * 8];

  f32x4 accO[4];
#pragma unroll
  for (int i = 0; i < 4; i++) accO[i] = (f32x4){0.f, 0.f, 0.f, 0.f};
  float mst[4] = {-__builtin_inff(), -__builtin_inff(), -__builtin_inff(),
                  -__builtin_inff()};
  float lsum[4] = {0.f, 0.f, 0.f, 0.f};

  const int nkt = (q0 + 47) >> 5;  // #k-tiles of 32 (covers rows q0..q0+15)
  for (int kt = 0; kt < nkt; ++kt) {
    const int k0 = kt * 32;
    f32x4 s[2];
    s[0] = (f32x4){0.f, 0.f, 0.f, 0.f};
    s[1] = (f32x4){0.f, 0.f, 0.f, 0.f};
#pragma unroll
    for (int nh = 0; nh < 2; nh++) {
#pragma unroll
      for (int dh = 0; dh < 2; dh++) {
        u16x8 kf =
            *(const u16x8*)&Kh[(k0 + nh * 16 + lr) * HD + dh * 32 + lg * 8];
        s[nh] = __builtin_amdgcn_mfma_f32_16x16x32_bf16(asbf(qf[dh]), asbf(kf),
                                                        s[nh], 0, 0, 0);
      }
    }
    if (kt == nkt - 1) {  // diagonal tile: causal mask
#pragma unroll
      for (int nh = 0; nh < 2; nh++)
#pragma unroll
        for (int r = 0; r < 4; r++) {
          int col = k0 + nh * 16 + lr, row = q0 + lg * 4 + r;
          if (col > row) s[nh][r] = -__builtin_inff();
        }
    }
    // online softmax (16-lane butterfly per row)
#pragma unroll
    for (int r = 0; r < 4; r++) {
      float smax = fmaxf(s[0][r], s[1][r]);
      smax = fmaxf(smax, __shfl_xor(smax, 1, 16));
      smax = fmaxf(smax, __shfl_xor(smax, 2, 16));
      smax = fmaxf(smax, __shfl_xor(smax, 4, 16));
      smax = fmaxf(smax, __shfl_xor(smax, 8, 16));
      float mnew = fmaxf(mst[r], smax);
      float corr = __expf(mst[r] - mnew);
      float p0 = __expf(s[0][r] - mnew);
      float p1 = __expf(s[1][r] - mnew);
      float ps = p0 + p1;
      ps += __shfl_xor(ps, 1, 16);
      ps += __shfl_xor(ps, 2, 16);
      ps += __shfl_xor(ps, 4, 16);
      ps += __shfl_xor(ps, 8, 16);
      lsum[r] = lsum[r] * corr + ps;
      mst[r] = mnew;
#pragma unroll
      for (int dt = 0; dt < 4; dt++) accO[dt][r] *= corr;
      const int row = lg * 4 + r;
      Plds[w][row][lr] = f2bf(p0);
      Plds[w][row][16 + lr] = f2bf(p1);
    }
    // PV: A = P (16x32) via LDS transpose; B = Vt rows (contiguous in t)
    u16x8 pa = *(const u16x8*)&Plds[w][lr][lg * 8];
#pragma unroll
    for (int dt = 0; dt < 4; dt++) {
      u16x8 vf = *(const u16x8*)&Vh[(dt * 16 + lr) * TT + k0 + lg * 8];
      accO[dt] = __builtin_amdgcn_mfma_f32_16x16x32_bf16(asbf(pa), asbf(vf),
                                                         accO[dt], 0, 0, 0);
    }
  }
  // epilogue -> AO [B][T][EMB] bf16
  const int b = bh >> 4, h = bh & 15;
#pragma unroll
  for (int dt = 0; dt < 4; dt++)
#pragma unroll
    for (int r = 0; r < 4; r++) {
      const int row = q0 + lg * 4 + r;
      const int d = h * 64 + dt * 16 + lr;
      float v = accO[dt][r] / lsum[r];
      AO[(b * TT + row) * EMB + d] = f2bf(v);
    }
}

// ---------- output projection GEMM (fp32 out + bias) ----------
__global__ __launch_bounds__(256) void k_gemm_out(const u16* __restrict__ AO,
                                                  const u16* __restrict__ WoT,
                                                  const float* __restrict__ bo,
                                                  float* __restrict__ out) {
  __shared__ u16 Al[128 * 32];
  __shared__ u16 Bl[128 * 32];
  const int tid = threadIdx.x;
  const int lane = tid & 63;
  const int w = tid >> 6;
  const int wr = w >> 1, wc = w & 1;
  const int lr = lane & 15, lg = lane >> 4;
  const int m0 = blockIdx.x * 128;
  const int n0 = blockIdx.y * 128;

  f32x4 acc[4][4];
#pragma unroll
  for (int i = 0; i < 4; i++)
#pragma unroll
    for (int j = 0; j < 4; j++) acc[i][j] = (f32x4){0.f, 0.f, 0.f, 0.f};

  const int srow = tid >> 2;
  const int scol = (tid & 3) * 8;
  const u16* ga0 = AO + (m0 + srow) * EMB + scol;
  const u16* gb0 = WoT + (n0 + srow) * EMB + scol;
  char* la0 = (char*)Al + w * 1024;
  char* lb0 = (char*)Bl + w * 1024;

  for (int k0 = 0; k0 < EMB; k0 += 32) {
    gload16(ga0 + k0, la0);
    gload16(ga0 + 64 * EMB + k0, la0 + 4096);
    gload16(gb0 + k0, lb0);
    gload16(gb0 + 64 * EMB + k0, lb0 + 4096);
    __syncthreads();
    u16x8 af[4], bfr[4];
#pragma unroll
    for (int mi = 0; mi < 4; mi++)
      af[mi] = *(const u16x8*)&Al[(wr * 64 + mi * 16 + lr) * 32 + lg * 8];
#pragma unroll
    for (int ni = 0; ni < 4; ni++)
      bfr[ni] = *(const u16x8*)&Bl[(wc * 64 + ni * 16 + lr) * 32 + lg * 8];
#pragma unroll
    for (int mi = 0; mi < 4; mi++)
#pragma unroll
      for (int ni = 0; ni < 4; ni++)
        acc[mi][ni] = __builtin_amdgcn_mfma_f32_16x16x32_bf16(
            asbf(af[mi]), asbf(bfr[ni]), acc[mi][ni], 0, 0, 0);
    __syncthreads();
  }

#pragma unroll
  for (int mi = 0; mi < 4; mi++) {
    const int lmb = wr * 64 + mi * 16 + lg * 4;
#pragma unroll
    for (int ni = 0; ni < 4; ni++) {
      const int ln = wc * 64 + ni * 16 + lr;
      const int n = n0 + ln;
      const float bv_ = bo[n];
#pragma unroll
      for (int r = 0; r < 4; r++) {
        const int m = m0 + lmb + r;
        out[m * EMB + n] = acc[mi][ni][r] + bv_;
      }
    }
  }
}

// ---------- launch ----------
extern "C" void kernel_launch(void* const* d_in, const int* in_sizes, int n_in,
                              void* d_out, int out_size, void* d_ws,
                              size_t ws_size, hipStream_t stream) {
  const float* x = (const float*)d_in[0];
  const float* Wq = (const float*)d_in[1];
  const float* bq = (const float*)d_in[2];
  const float* Wk = (const float*)d_in[3];
  const float* bk = (const float*)d_in[4];
  const float* Wv = (const float*)d_in[5];
  const float* bv = (const float*)d_in[6];
  const float* Wo = (const float*)d_in[7];
  const float* bo = (const float*)d_in[8];
  float* out = (float*)d_out;

  char* ws = (char*)d_ws;
  u16* xb = (u16*)ws;                      // 8 MB (reused as AO)
  u16* WqT = (u16*)(ws + (8u << 20));      // 2 MB
  u16* WkT = (u16*)(ws + (10u << 20));     // 2 MB
  u16* WvT = (u16*)(ws + (12u << 20));     // 2 MB
  u16* WoT = (u16*)(ws + (14u << 20));     // 2 MB
  u16* Qb = (u16*)(ws + (16u << 20));      // 8 MB
  u16* Kb = (u16*)(ws + (24u << 20));      // 8 MB
  u16* Vtb = (u16*)(ws + (32u << 20));     // 8 MB (total 40 MB)
  u16* AO = xb;

  k_conv_x<<<2048, 256, 0, stream>>>(x, xb);
  dim3 tg(32, 32);
  k_conv_wT<<<tg, 256, 0, stream>>>(Wq, WqT);
  k_conv_wT<<<tg, 256, 0, stream>>>(Wk, WkT);
  k_conv_wT<<<tg, 256, 0, stream>>>(Wv, WvT);
  k_conv_wT<<<tg, 256, 0, stream>>>(Wo, WoT);
  k_gemm_qkv<<<dim3(32, 24), 256, 0, stream>>>(xb, WqT, WkT, WvT, bq, bk, bv,
                                               Qb, Kb, Vtb);
  k_attn<<<1024, 256, 0, stream>>>(Qb, Kb, Vtb, AO);
  k_gemm_out<<<dim3(32, 8), 256, 0, stream>>>(AO, WoT, bo, out);
}

// Round 2
// 306.257 us; speedup vs baseline: 1.0110x; 1.0110x over previous
//
#include <hip/hip_runtime.h>

typedef unsigned short u16;
typedef u16 u16x8 __attribute__((ext_vector_type(8)));
typedef __bf16 bf16x8 __attribute__((ext_vector_type(8)));
typedef float f32x4 __attribute__((ext_vector_type(4)));

#define EMB 1024
#define TT 2048
#define BB 2
#define NHEADS 16
#define HD 64
#define MTOT (BB * TT)  // 4096

// ---------- helpers ----------
__device__ __forceinline__ u16 f2bf(float f) {
  unsigned u = __builtin_bit_cast(unsigned, f);
  u += 0x7fffu + ((u >> 16) & 1u);
  return (u16)(u >> 16);
}

__device__ __forceinline__ bf16x8 asbf(u16x8 v) {
  return __builtin_bit_cast(bf16x8, v);
}

__device__ __forceinline__ void gload16(const void* g, void* l) {
  __builtin_amdgcn_global_load_lds(
      (const __attribute__((address_space(1))) void*)g,
      (__attribute__((address_space(3))) void*)l, 16, 0, 0);
}

// ---------- conversion kernels ----------
__global__ __launch_bounds__(256) void k_conv_x(const float* __restrict__ x,
                                                u16* __restrict__ xb) {
  int i = blockIdx.x * 256 + threadIdx.x;  // 8 elems per thread
  float4 a = ((const float4*)x)[i * 2];
  float4 b = ((const float4*)x)[i * 2 + 1];
  u16x8 o;
  o[0] = f2bf(a.x); o[1] = f2bf(a.y); o[2] = f2bf(a.z); o[3] = f2bf(a.w);
  o[4] = f2bf(b.x); o[5] = f2bf(b.y); o[6] = f2bf(b.z); o[7] = f2bf(b.w);
  ((u16x8*)xb)[i] = o;
}

// W[k][n] fp32 -> Wt[n][k] bf16 (LDS-tiled transpose), 4 matrices via grid.z
__global__ __launch_bounds__(256) void k_conv_wT4(
    const float* __restrict__ W0, const float* __restrict__ W1,
    const float* __restrict__ W2, const float* __restrict__ W3,
    u16* __restrict__ T0, u16* __restrict__ T1, u16* __restrict__ T2,
    u16* __restrict__ T3) {
  const int z = blockIdx.z;
  const float* __restrict__ W = (z == 0) ? W0 : (z == 1) ? W1 : (z == 2) ? W2 : W3;
  u16* __restrict__ Wt = (z == 0) ? T0 : (z == 1) ? T1 : (z == 2) ? T2 : T3;
  __shared__ float tile[32][33];
  int bx = blockIdx.x * 32, by = blockIdx.y * 32;
  int tx = threadIdx.x & 31;
  int ty = threadIdx.x >> 5;  // 0..7
#pragma unroll
  for (int r = ty; r < 32; r += 8) tile[r][tx] = W[(by + r) * EMB + bx + tx];
  __syncthreads();
#pragma unroll
  for (int r = ty; r < 32; r += 8)
    Wt[(bx + r) * EMB + by + tx] = f2bf(tile[tx][r]);
}

// ---------- fused QKV GEMM ----------
__global__ __launch_bounds__(256) void k_gemm_qkv(
    const u16* __restrict__ xb, const u16* __restrict__ WqT,
    const u16* __restrict__ WkT, const u16* __restrict__ WvT,
    const float* __restrict__ bq, const float* __restrict__ bk,
    const float* __restrict__ bv, u16* __restrict__ Q, u16* __restrict__ K,
    u16* __restrict__ Vt) {
  __shared__ u16 Al[128 * 32];
  __shared__ u16 Bl[128 * 32];
  const int tid = threadIdx.x;
  const int lane = tid & 63;
  const int w = tid >> 6;
  const int wr = w >> 1, wc = w & 1;
  const int lr = lane & 15, lg = lane >> 4;
  const int m0 = blockIdx.x * 128;
  const int nb = blockIdx.y;           // 0..23
  const int seg = nb >> 3;             // 0=Q 1=K 2=V
  const int n0 = (nb & 7) * 128;
  const u16* __restrict__ Bt = (seg == 0) ? WqT : (seg == 1) ? WkT : WvT;
  const float* __restrict__ bias = (seg == 0) ? bq : (seg == 1) ? bk : bv;

  f32x4 acc[4][4];
#pragma unroll
  for (int i = 0; i < 4; i++)
#pragma unroll
    for (int j = 0; j < 4; j++) acc[i][j] = (f32x4){0.f, 0.f, 0.f, 0.f};

  const int srow = tid >> 2;           // 0..63
  const int scol = (tid & 3) * 8;
  const u16* ga0 = xb + (m0 + srow) * EMB + scol;
  const u16* gb0 = Bt + (n0 + srow) * EMB + scol;
  char* la0 = (char*)Al + w * 1024;    // wave-uniform LDS base
  char* lb0 = (char*)Bl + w * 1024;

  for (int k0 = 0; k0 < EMB; k0 += 32) {
    gload16(ga0 + k0, la0);
    gload16(ga0 + 64 * EMB + k0, la0 + 4096);
    gload16(gb0 + k0, lb0);
    gload16(gb0 + 64 * EMB + k0, lb0 + 4096);
    __syncthreads();
    u16x8 af[4], bfr[4];
#pragma unroll
    for (int mi = 0; mi < 4; mi++)
      af[mi] = *(const u16x8*)&Al[(wr * 64 + mi * 16 + lr) * 32 + lg * 8];
#pragma unroll
    for (int ni = 0; ni < 4; ni++)
      bfr[ni] = *(const u16x8*)&Bl[(wc * 64 + ni * 16 + lr) * 32 + lg * 8];
#pragma unroll
    for (int mi = 0; mi < 4; mi++)
#pragma unroll
      for (int ni = 0; ni < 4; ni++)
        acc[mi][ni] = __builtin_amdgcn_mfma_f32_16x16x32_bf16(
            asbf(af[mi]), asbf(bfr[ni]), acc[mi][ni], 0, 0, 0);
    __syncthreads();
  }

#pragma unroll
  for (int mi = 0; mi < 4; mi++) {
    const int lmb = wr * 64 + mi * 16 + lg * 4;
#pragma unroll
    for (int ni = 0; ni < 4; ni++) {
      const int ln = wc * 64 + ni * 16 + lr;
      const int n = n0 + ln;
      const float bv_ = bias[n];
      const int h = n >> 6, d = n & 63;
#pragma unroll
      for (int r = 0; r < 4; r++) {
        const int m = m0 + lmb + r;
        const int b = m >> 11, t = m & 2047;
        float v = acc[mi][ni][r] + bv_;
        if (seg == 0) {
          v *= 0.125f;  // fold 1/sqrt(D) into Q (exact pow2)
          Q[(((b * NHEADS + h) * TT) + t) * HD + d] = f2bf(v);
        } else if (seg == 1) {
          K[(((b * NHEADS + h) * TT) + t) * HD + d] = f2bf(v);
        } else {
          Vt[(((b * NHEADS + h) * HD) + d) * TT + t] = f2bf(v);
        }
      }
    }
  }
}

// ---------- causal flash attention ----------
// grid: 32 (b*h) * 32 (q-blocks of 64); 4 waves, each owns a 16-row q-tile.
// KVBLK=64, K/V straight from global (L2-resident). Longest-first order.
__global__ __launch_bounds__(256) void k_attn(const u16* __restrict__ Q,
                                              const u16* __restrict__ Kg,
                                              const u16* __restrict__ Vt,
                                              u16* __restrict__ AO) {
  __shared__ u16 Plds[4][16][68];  // pad 64->68: write banks 0/8/16/24 per lg
  const int tid = threadIdx.x;
  const int lane = tid & 63;
  const int w = tid >> 6;
  const int lr = lane & 15, lg = lane >> 4;
  const int bh = blockIdx.x >> 5;              // 0..31
  const int qb = 31 - (blockIdx.x & 31);       // longest work first
  const int q0 = qb * 64 + w * 16;
  const u16* __restrict__ Qh = Q + bh * TT * HD;
  const u16* __restrict__ Kh = Kg + bh * TT * HD;
  const u16* __restrict__ Vh = Vt + bh * HD * TT;

  u16x8 qf[2];
  qf[0] = *(const u16x8*)&Qh[(q0 + lr) * HD + lg * 8];
  qf[1] = *(const u16x8*)&Qh[(q0 + lr) * HD + 32 + lg * 8];

  f32x4 accO[4];
#pragma unroll
  for (int i = 0; i < 4; i++) accO[i] = (f32x4){0.f, 0.f, 0.f, 0.f};
  float mst[4] = {-__builtin_inff(), -__builtin_inff(), -__builtin_inff(),
                  -__builtin_inff()};
  float lsum[4] = {0.f, 0.f, 0.f, 0.f};  // per-lane partial sums (deferred)

  const int nkt = (q0 + 79) >> 6;  // #k-tiles of 64 covering cols 0..q0+15
  for (int kt = 0; kt < nkt; ++kt) {
    const int k0 = kt * 64;
    f32x4 s[4];
#pragma unroll
    for (int n = 0; n < 4; n++) s[n] = (f32x4){0.f, 0.f, 0.f, 0.f};
    __builtin_amdgcn_s_setprio(1);
#pragma unroll
    for (int n = 0; n < 4; n++) {
#pragma unroll
      for (int dh = 0; dh < 2; dh++) {
        u16x8 kf =
            *(const u16x8*)&Kh[(k0 + n * 16 + lr) * HD + dh * 32 + lg * 8];
        s[n] = __builtin_amdgcn_mfma_f32_16x16x32_bf16(asbf(qf[dh]), asbf(kf),
                                                       s[n], 0, 0, 0);
      }
    }
    __builtin_amdgcn_s_setprio(0);
    if (kt == nkt - 1) {  // only the last tile can cross the diagonal
#pragma unroll
      for (int n = 0; n < 4; n++)
#pragma unroll
        for (int r = 0; r < 4; r++) {
          int col = k0 + n * 16 + lr, row = q0 + lg * 4 + r;
          if (col > row) s[n][r] = -__builtin_inff();
        }
    }
    // online softmax: max butterfly only; row-sum deferred (corr row-uniform)
#pragma unroll
    for (int r = 0; r < 4; r++) {
      float smax = fmaxf(fmaxf(s[0][r], s[1][r]), fmaxf(s[2][r], s[3][r]));
      smax = fmaxf(smax, __shfl_xor(smax, 1, 16));
      smax = fmaxf(smax, __shfl_xor(smax, 2, 16));
      smax = fmaxf(smax, __shfl_xor(smax, 4, 16));
      smax = fmaxf(smax, __shfl_xor(smax, 8, 16));
      float mnew = fmaxf(mst[r], smax);
      float corr = __expf(mst[r] - mnew);
      float p0 = __expf(s[0][r] - mnew);
      float p1 = __expf(s[1][r] - mnew);
      float p2 = __expf(s[2][r] - mnew);
      float p3 = __expf(s[3][r] - mnew);
      lsum[r] = lsum[r] * corr + (p0 + p1) + (p2 + p3);
      mst[r] = mnew;
#pragma unroll
      for (int dt = 0; dt < 4; dt++) accO[dt][r] *= corr;
      const int row = lg * 4 + r;
      Plds[w][row][lr] = f2bf(p0);
      Plds[w][row][16 + lr] = f2bf(p1);
      Plds[w][row][32 + lr] = f2bf(p2);
      Plds[w][row][48 + lr] = f2bf(p3);
    }
    // PV: A = P (16x64) via LDS transpose; B = Vt rows (contiguous in t)
    u16x8 pa0 = *(const u16x8*)&Plds[w][lr][lg * 8];
    u16x8 pa1 = *(const u16x8*)&Plds[w][lr][32 + lg * 8];
    __builtin_amdgcn_s_setprio(1);
#pragma unroll
    for (int dt = 0; dt < 4; dt++) {
      u16x8 vf0 = *(const u16x8*)&Vh[(dt * 16 + lr) * TT + k0 + lg * 8];
      u16x8 vf1 = *(const u16x8*)&Vh[(dt * 16 + lr) * TT + k0 + 32 + lg * 8];
      accO[dt] = __builtin_amdgcn_mfma_f32_16x16x32_bf16(asbf(pa0), asbf(vf0),
                                                         accO[dt], 0, 0, 0);
      accO[dt] = __builtin_amdgcn_mfma_f32_16x16x32_bf16(asbf(pa1), asbf(vf1),
                                                         accO[dt], 0, 0, 0);
    }
    __builtin_amdgcn_s_setprio(0);
  }
  // final row-sum butterfly + epilogue -> AO [B][T][EMB] bf16
  float rinv[4];
#pragma unroll
  for (int r = 0; r < 4; r++) {
    float t = lsum[r];
    t += __shfl_xor(t, 1, 16);
    t += __shfl_xor(t, 2, 16);
    t += __shfl_xor(t, 4, 16);
    t += __shfl_xor(t, 8, 16);
    rinv[r] = 1.0f / t;
  }
  const int b = bh >> 4, h = bh & 15;
#pragma unroll
  for (int dt = 0; dt < 4; dt++)
#pragma unroll
    for (int r = 0; r < 4; r++) {
      const int row = q0 + lg * 4 + r;
      const int d = h * 64 + dt * 16 + lr;
      AO[(b * TT + row) * EMB + d] = f2bf(accO[dt][r] * rinv[r]);
    }
}

// ---------- output projection GEMM (fp32 out + bias) ----------
__global__ __launch_bounds__(256) void k_gemm_out(const u16* __restrict__ AO,
                                                  const u16* __restrict__ WoT,
                                                  const float* __restrict__ bo,
                                                  float* __restrict__ out) {
  __shared__ u16 Al[128 * 32];
  __shared__ u16 Bl[128 * 32];
  const int tid = threadIdx.x;
  const int lane = tid & 63;
  const int w = tid >> 6;
  const int wr = w >> 1, wc = w & 1;
  const int lr = lane & 15, lg = lane >> 4;
  const int m0 = blockIdx.x * 128;
  const int n0 = blockIdx.y * 128;

  f32x4 acc[4][4];
#pragma unroll
  for (int i = 0; i < 4; i++)
#pragma unroll
    for (int j = 0; j < 4; j++) acc[i][j] = (f32x4){0.f, 0.f, 0.f, 0.f};

  const int srow = tid >> 2;
  const int scol = (tid & 3) * 8;
  const u16* ga0 = AO + (m0 + srow) * EMB + scol;
  const u16* gb0 = WoT + (n0 + srow) * EMB + scol;
  char* la0 = (char*)Al + w * 1024;
  char* lb0 = (char*)Bl + w * 1024;

  for (int k0 = 0; k0 < EMB; k0 += 32) {
    gload16(ga0 + k0, la0);
    gload16(ga0 + 64 * EMB + k0, la0 + 4096);
    gload16(gb0 + k0, lb0);
    gload16(gb0 + 64 * EMB + k0, lb0 + 4096);
    __syncthreads();
    u16x8 af[4], bfr[4];
#pragma unroll
    for (int mi = 0; mi < 4; mi++)
      af[mi] = *(const u16x8*)&Al[(wr * 64 + mi * 16 + lr) * 32 + lg * 8];
#pragma unroll
    for (int ni = 0; ni < 4; ni++)
      bfr[ni] = *(const u16x8*)&Bl[(wc * 64 + ni * 16 + lr) * 32 + lg * 8];
#pragma unroll
    for (int mi = 0; mi < 4; mi++)
#pragma unroll
      for (int ni = 0; ni < 4; ni++)
        acc[mi][ni] = __builtin_amdgcn_mfma_f32_16x16x32_bf16(
            asbf(af[mi]), asbf(bfr[ni]), acc[mi][ni], 0, 0, 0);
    __syncthreads();
  }

#pragma unroll
  for (int mi = 0; mi < 4; mi++) {
    const int lmb = wr * 64 + mi * 16 + lg * 4;
#pragma unroll
    for (int ni = 0; ni < 4; ni++) {
      const int ln = wc * 64 + ni * 16 + lr;
      const int n = n0 + ln;
      const float bv_ = bo[n];
#pragma unroll
      for (int r = 0; r < 4; r++) {
        const int m = m0 + lmb + r;
        out[m * EMB + n] = acc[mi][ni][r] + bv_;
      }
    }
  }
}

// ---------- launch ----------
extern "C" void kernel_launch(void* const* d_in, const int* in_sizes, int n_in,
                              void* d_out, int out_size, void* d_ws,
                              size_t ws_size, hipStream_t stream) {
  const float* x = (const float*)d_in[0];
  const float* Wq = (const float*)d_in[1];
  const float* bq = (const float*)d_in[2];
  const float* Wk = (const float*)d_in[3];
  const float* bk = (const float*)d_in[4];
  const float* Wv = (const float*)d_in[5];
  const float* bv = (const float*)d_in[6];
  const float* Wo = (const float*)d_in[7];
  const float* bo = (const float*)d_in[8];
  float* out = (float*)d_out;

  char* ws = (char*)d_ws;
  u16* xb = (u16*)ws;                      // 8 MB (reused as AO)
  u16* WqT = (u16*)(ws + (8u << 20));      // 2 MB
  u16* WkT = (u16*)(ws + (10u << 20));     // 2 MB
  u16* WvT = (u16*)(ws + (12u << 20));     // 2 MB
  u16* WoT = (u16*)(ws + (14u << 20));     // 2 MB
  u16* Qb = (u16*)(ws + (16u << 20));      // 8 MB
  u16* Kb = (u16*)(ws + (24u << 20));      // 8 MB
  u16* Vtb = (u16*)(ws + (32u << 20));     // 8 MB (total 40 MB)
  u16* AO = xb;

  k_conv_x<<<2048, 256, 0, stream>>>(x, xb);
  dim3 tg(32, 32, 4);
  k_conv_wT4<<<tg, 256, 0, stream>>>(Wq, Wk, Wv, Wo, WqT, WkT, WvT, WoT);
  k_gemm_qkv<<<dim3(32, 24), 256, 0, stream>>>(xb, WqT, WkT, WvT, bq, bk, bv,
                                               Qb, Kb, Vtb);
  k_attn<<<1024, 256, 0, stream>>>(Qb, Kb, Vtb, AO);
  k_gemm_out<<<dim3(32, 8), 256, 0, stream>>>(AO, WoT, bo, out);
}

// Round 4
// 190.875 us; speedup vs baseline: 1.6221x; 1.6045x over previous
//
#include <hip/hip_runtime.h>

typedef unsigned short u16;
typedef u16 u16x8 __attribute__((ext_vector_type(8)));
typedef __bf16 bf16x8 __attribute__((ext_vector_type(8)));
typedef float f32x4 __attribute__((ext_vector_type(4)));

#define EMB 1024
#define TT 2048
#define BB 2
#define NHEADS 16
#define HD 64
#define MTOT (BB * TT)  // 4096

// ---------- helpers ----------
__device__ __forceinline__ u16 f2bf(float f) {
  unsigned u = __builtin_bit_cast(unsigned, f);
  u += 0x7fffu + ((u >> 16) & 1u);
  return (u16)(u >> 16);
}

__device__ __forceinline__ bf16x8 asbf(u16x8 v) {
  return __builtin_bit_cast(bf16x8, v);
}

__device__ __forceinline__ void gload16(const void* g, void* l) {
  __builtin_amdgcn_global_load_lds(
      (const __attribute__((address_space(1))) void*)g,
      (__attribute__((address_space(3))) void*)l, 16, 0, 0);
}

// ---------- conversion kernels ----------
__global__ __launch_bounds__(256) void k_conv_x(const float* __restrict__ x,
                                                u16* __restrict__ xb) {
  int i = blockIdx.x * 256 + threadIdx.x;  // 8 elems per thread
  float4 a = ((const float4*)x)[i * 2];
  float4 b = ((const float4*)x)[i * 2 + 1];
  u16x8 o;
  o[0] = f2bf(a.x); o[1] = f2bf(a.y); o[2] = f2bf(a.z); o[3] = f2bf(a.w);
  o[4] = f2bf(b.x); o[5] = f2bf(b.y); o[6] = f2bf(b.z); o[7] = f2bf(b.w);
  ((u16x8*)xb)[i] = o;
}

// W[k][n] fp32 -> Wt[n][k] bf16 (LDS-tiled transpose), 4 matrices via grid.z
__global__ __launch_bounds__(256) void k_conv_wT4(
    const float* __restrict__ W0, const float* __restrict__ W1,
    const float* __restrict__ W2, const float* __restrict__ W3,
    u16* __restrict__ T0, u16* __restrict__ T1, u16* __restrict__ T2,
    u16* __restrict__ T3) {
  const int z = blockIdx.z;
  const float* __restrict__ W = (z == 0) ? W0 : (z == 1) ? W1 : (z == 2) ? W2 : W3;
  u16* __restrict__ Wt = (z == 0) ? T0 : (z == 1) ? T1 : (z == 2) ? T2 : T3;
  __shared__ float tile[32][33];
  int bx = blockIdx.x * 32, by = blockIdx.y * 32;
  int tx = threadIdx.x & 31;
  int ty = threadIdx.x >> 5;  // 0..7
#pragma unroll
  for (int r = ty; r < 32; r += 8) tile[r][tx] = W[(by + r) * EMB + bx + tx];
  __syncthreads();
#pragma unroll
  for (int r = ty; r < 32; r += 8)
    Wt[(bx + r) * EMB + by + tx] = f2bf(tile[tx][r]);
}

// ---------- fused QKV GEMM ----------
__global__ __launch_bounds__(256) void k_gemm_qkv(
    const u16* __restrict__ xb, const u16* __restrict__ WqT,
    const u16* __restrict__ WkT, const u16* __restrict__ WvT,
    const float* __restrict__ bq, const float* __restrict__ bk,
    const float* __restrict__ bv, u16* __restrict__ Q, u16* __restrict__ K,
    u16* __restrict__ Vt) {
  __shared__ u16 Al[128 * 32];
  __shared__ u16 Bl[128 * 32];
  const int tid = threadIdx.x;
  const int lane = tid & 63;
  const int w = tid >> 6;
  const int wr = w >> 1, wc = w & 1;
  const int lr = lane & 15, lg = lane >> 4;
  const int m0 = blockIdx.x * 128;
  const int nb = blockIdx.y;           // 0..23
  const int seg = nb >> 3;             // 0=Q 1=K 2=V
  const int n0 = (nb & 7) * 128;
  const u16* __restrict__ Bt = (seg == 0) ? WqT : (seg == 1) ? WkT : WvT;
  const float* __restrict__ bias = (seg == 0) ? bq : (seg == 1) ? bk : bv;

  f32x4 acc[4][4];
#pragma unroll
  for (int i = 0; i < 4; i++)
#pragma unroll
    for (int j = 0; j < 4; j++) acc[i][j] = (f32x4){0.f, 0.f, 0.f, 0.f};

  const int srow = tid >> 2;           // 0..63
  const int scol = (tid & 3) * 8;
  const u16* ga0 = xb + (m0 + srow) * EMB + scol;
  const u16* gb0 = Bt + (n0 + srow) * EMB + scol;
  char* la0 = (char*)Al + w * 1024;    // wave-uniform LDS base
  char* lb0 = (char*)Bl + w * 1024;

  for (int k0 = 0; k0 < EMB; k0 += 32) {
    gload16(ga0 + k0, la0);
    gload16(ga0 + 64 * EMB + k0, la0 + 4096);
    gload16(gb0 + k0, lb0);
    gload16(gb0 + 64 * EMB + k0, lb0 + 4096);
    __syncthreads();
    u16x8 af[4], bfr[4];
#pragma unroll
    for (int mi = 0; mi < 4; mi++)
      af[mi] = *(const u16x8*)&Al[(wr * 64 + mi * 16 + lr) * 32 + lg * 8];
#pragma unroll
    for (int ni = 0; ni < 4; ni++)
      bfr[ni] = *(const u16x8*)&Bl[(wc * 64 + ni * 16 + lr) * 32 + lg * 8];
#pragma unroll
    for (int mi = 0; mi < 4; mi++)
#pragma unroll
      for (int ni = 0; ni < 4; ni++)
        acc[mi][ni] = __builtin_amdgcn_mfma_f32_16x16x32_bf16(
            asbf(af[mi]), asbf(bfr[ni]), acc[mi][ni], 0, 0, 0);
    __syncthreads();
  }

#pragma unroll
  for (int mi = 0; mi < 4; mi++) {
    const int lmb = wr * 64 + mi * 16 + lg * 4;
#pragma unroll
    for (int ni = 0; ni < 4; ni++) {
      const int ln = wc * 64 + ni * 16 + lr;
      const int n = n0 + ln;
      const float bv_ = bias[n];
      const int h = n >> 6, d = n & 63;
#pragma unroll
      for (int r = 0; r < 4; r++) {
        const int m = m0 + lmb + r;
        const int b = m >> 11, t = m & 2047;
        float v = acc[mi][ni][r] + bv_;
        if (seg == 0) {
          v *= 0.125f;  // fold 1/sqrt(D) into Q (exact pow2)
          Q[(((b * NHEADS + h) * TT) + t) * HD + d] = f2bf(v);
        } else if (seg == 1) {
          K[(((b * NHEADS + h) * TT) + t) * HD + d] = f2bf(v);
        } else {
          Vt[(((b * NHEADS + h) * HD) + d) * TT + t] = f2bf(v);
        }
      }
    }
  }
}

// ---------- causal flash attention ----------
// grid: 32 (b*h) * 32 (64-row q-blocks); 4 waves, each owns a 16-row q-tile.
// KVBLK=64. K/V staged per-BLOCK into double-buffered, XOR-swizzled LDS via
// global_load_lds; tile kt+1 issued before computing tile kt (2-phase T3).
__global__ __launch_bounds__(256) void k_attn(const u16* __restrict__ Q,
                                              const u16* __restrict__ Kg,
                                              const u16* __restrict__ Vt,
                                              u16* __restrict__ AO) {
  __shared__ u16 Kl[2][64 * 64];   // 8KB x2
  __shared__ u16 Vl[2][64 * 64];   // 8KB x2
  __shared__ u16 Plds[4][16][68];  // padded: 0 conflicts (measured r1)
  const int tid = threadIdx.x;
  const int lane = tid & 63;
  const int w = tid >> 6;
  const int lr = lane & 15, lg = lane >> 4;
  const int bh = blockIdx.x >> 5;              // 0..31
  const int qb = 31 - (blockIdx.x & 31);       // longest work first
  const int q0 = qb * 64 + w * 16;
  const u16* __restrict__ Qh = Q + bh * TT * HD;
  const u16* __restrict__ Kh = Kg + bh * TT * HD;
  const u16* __restrict__ Vh = Vt + bh * HD * TT;

  // staging geometry: tile row = 128B; lane l of wave w writes phys bytes
  // l*16 of quarter p*4096+w*1024 == row-linear chunk (l&7) of row
  // p*32+w*8+(l>>3). Swizzle: phys chunk c holds global chunk c^(row&7)
  // (rule 21: linear LDS dest + pre-swizzled global source + swz read).
  const int srow = tid >> 3;                   // 0..31 (row within half-tile)
  const int sc = (tid & 7) ^ (srow & 7);       // pre-swizzled 16B chunk

  u16x8 qf[2];
  qf[0] = *(const u16x8*)&Qh[(q0 + lr) * HD + lg * 8];
  qf[1] = *(const u16x8*)&Qh[(q0 + lr) * HD + 32 + lg * 8];

  f32x4 accO[4];
#pragma unroll
  for (int i = 0; i < 4; i++) accO[i] = (f32x4){0.f, 0.f, 0.f, 0.f};
  float mst[4] = {-__builtin_inff(), -__builtin_inff(), -__builtin_inff(),
                  -__builtin_inff()};
  float lsum[4] = {0.f, 0.f, 0.f, 0.f};  // per-lane partials (deferred sum)

  const int nkt = qb + 1;  // block-uniform k-tile count (mask covers tail)

  // prologue: stage tile 0 into buf 0
#pragma unroll
  for (int p = 0; p < 2; p++) {
    const int row = p * 32 + srow;
    gload16(Kh + (0 + row) * HD + sc * 8,
            (char*)Kl[0] + p * 4096 + w * 1024);
    gload16(Vh + row * TT + 0 + sc * 8,
            (char*)Vl[0] + p * 4096 + w * 1024);
  }
  __syncthreads();  // drains vmcnt

  for (int kt = 0; kt < nkt; ++kt) {
    const int k0 = kt * 64;
    const int cur = kt & 1;
    if (kt + 1 < nkt) {  // issue next-tile loads BEFORE compute (2-phase)
      const int kn = k0 + 64;
#pragma unroll
      for (int p = 0; p < 2; p++) {
        const int row = p * 32 + srow;
        gload16(Kh + (kn + row) * HD + sc * 8,
                (char*)Kl[cur ^ 1] + p * 4096 + w * 1024);
        gload16(Vh + row * TT + kn + sc * 8,
                (char*)Vl[cur ^ 1] + p * 4096 + w * 1024);
      }
    }
    const char* Kc = (const char*)Kl[cur];
    const char* Vc = (const char*)Vl[cur];

    f32x4 s[4];
#pragma unroll
    for (int n = 0; n < 4; n++) s[n] = (f32x4){0.f, 0.f, 0.f, 0.f};
    __builtin_amdgcn_s_setprio(1);
#pragma unroll
    for (int n = 0; n < 4; n++) {
      const int row = n * 16 + lr;
#pragma unroll
      for (int dh = 0; dh < 2; dh++) {
        const int bo = (dh * 64 + lg * 16) ^ ((row & 7) << 4);
        u16x8 kf = *(const u16x8*)(Kc + row * 128 + bo);
        s[n] = __builtin_amdgcn_mfma_f32_16x16x32_bf16(asbf(qf[dh]), asbf(kf),
                                                       s[n], 0, 0, 0);
      }
    }
    __builtin_amdgcn_s_setprio(0);
    if (kt == nkt - 1) {  // only the last tile can cross the diagonal
#pragma unroll
      for (int n = 0; n < 4; n++)
#pragma unroll
        for (int r = 0; r < 4; r++) {
          int col = k0 + n * 16 + lr, row = q0 + lg * 4 + r;
          if (col > row) s[n][r] = -__builtin_inff();
        }
    }
    // online softmax: max butterfly only; row-sum deferred (corr row-uniform)
#pragma unroll
    for (int r = 0; r < 4; r++) {
      float smax = fmaxf(fmaxf(s[0][r], s[1][r]), fmaxf(s[2][r], s[3][r]));
      smax = fmaxf(smax, __shfl_xor(smax, 1, 16));
      smax = fmaxf(smax, __shfl_xor(smax, 2, 16));
      smax = fmaxf(smax, __shfl_xor(smax, 4, 16));
      smax = fmaxf(smax, __shfl_xor(smax, 8, 16));
      float mnew = fmaxf(mst[r], smax);
      float corr = __expf(mst[r] - mnew);
      float p0 = __expf(s[0][r] - mnew);
      float p1 = __expf(s[1][r] - mnew);
      float p2 = __expf(s[2][r] - mnew);
      float p3 = __expf(s[3][r] - mnew);
      lsum[r] = lsum[r] * corr + (p0 + p1) + (p2 + p3);
      mst[r] = mnew;
#pragma unroll
      for (int dt = 0; dt < 4; dt++) accO[dt][r] *= corr;
      const int row = lg * 4 + r;
      Plds[w][row][lr] = f2bf(p0);
      Plds[w][row][16 + lr] = f2bf(p1);
      Plds[w][row][32 + lr] = f2bf(p2);
      Plds[w][row][48 + lr] = f2bf(p3);
    }
    // PV: A = P (16x64) via LDS transpose; B = V rows from swizzled LDS
    u16x8 pa0 = *(const u16x8*)&Plds[w][lr][lg * 8];
    u16x8 pa1 = *(const u16x8*)&Plds[w][lr][32 + lg * 8];
    __builtin_amdgcn_s_setprio(1);
#pragma unroll
    for (int dt = 0; dt < 4; dt++) {
      const int row = dt * 16 + lr;
      const int bo0 = (lg * 16) ^ ((row & 7) << 4);
      const int bo1 = (64 + lg * 16) ^ ((row & 7) << 4);
      u16x8 vf0 = *(const u16x8*)(Vc + row * 128 + bo0);
      u16x8 vf1 = *(const u16x8*)(Vc + row * 128 + bo1);
      accO[dt] = __builtin_amdgcn_mfma_f32_16x16x32_bf16(asbf(pa0), asbf(vf0),
                                                         accO[dt], 0, 0, 0);
      accO[dt] = __builtin_amdgcn_mfma_f32_16x16x32_bf16(asbf(pa1), asbf(vf1),
                                                         accO[dt], 0, 0, 0);
    }
    __builtin_amdgcn_s_setprio(0);
    __syncthreads();  // drains vmcnt: buf cur^1 staged; buf cur free to write
  }
  // final row-sum butterfly + epilogue -> AO [B][T][EMB] bf16
  float rinv[4];
#pragma unroll
  for (int r = 0; r < 4; r++) {
    float t = lsum[r];
    t += __shfl_xor(t, 1, 16);
    t += __shfl_xor(t, 2, 16);
    t += __shfl_xor(t, 4, 16);
    t += __shfl_xor(t, 8, 16);
    rinv[r] = 1.0f / t;
  }
  const int b = bh >> 4, h = bh & 15;
#pragma unroll
  for (int dt = 0; dt < 4; dt++)
#pragma unroll
    for (int r = 0; r < 4; r++) {
      const int row = q0 + lg * 4 + r;
      const int d = h * 64 + dt * 16 + lr;
      AO[(b * TT + row) * EMB + d] = f2bf(accO[dt][r] * rinv[r]);
    }
}

// ---------- output projection GEMM (fp32 out + bias) ----------
__global__ __launch_bounds__(256) void k_gemm_out(const u16* __restrict__ AO,
                                                  const u16* __restrict__ WoT,
                                                  const float* __restrict__ bo,
                                                  float* __restrict__ out) {
  __shared__ u16 Al[128 * 32];
  __shared__ u16 Bl[128 * 32];
  const int tid = threadIdx.x;
  const int lane = tid & 63;
  const int w = tid >> 6;
  const int wr = w >> 1, wc = w & 1;
  const int lr = lane & 15, lg = lane >> 4;
  const int m0 = blockIdx.x * 128;
  const int n0 = blockIdx.y * 128;

  f32x4 acc[4][4];
#pragma unroll
  for (int i = 0; i < 4; i++)
#pragma unroll
    for (int j = 0; j < 4; j++) acc[i][j] = (f32x4){0.f, 0.f, 0.f, 0.f};

  const int srow = tid >> 2;
  const int scol = (tid & 3) * 8;
  const u16* ga0 = AO + (m0 + srow) * EMB + scol;
  const u16* gb0 = WoT + (n0 + srow) * EMB + scol;
  char* la0 = (char*)Al + w * 1024;
  char* lb0 = (char*)Bl + w * 1024;

  for (int k0 = 0; k0 < EMB; k0 += 32) {
    gload16(ga0 + k0, la0);
    gload16(ga0 + 64 * EMB + k0, la0 + 4096);
    gload16(gb0 + k0, lb0);
    gload16(gb0 + 64 * EMB + k0, lb0 + 4096);
    __syncthreads();
    u16x8 af[4], bfr[4];
#pragma unroll
    for (int mi = 0; mi < 4; mi++)
      af[mi] = *(const u16x8*)&Al[(wr * 64 + mi * 16 + lr) * 32 + lg * 8];
#pragma unroll
    for (int ni = 0; ni < 4; ni++)
      bfr[ni] = *(const u16x8*)&Bl[(wc * 64 + ni * 16 + lr) * 32 + lg * 8];
#pragma unroll
    for (int mi = 0; mi < 4; mi++)
#pragma unroll
      for (int ni = 0; ni < 4; ni++)
        acc[mi][ni] = __builtin_amdgcn_mfma_f32_16x16x32_bf16(
            asbf(af[mi]), asbf(bfr[ni]), acc[mi][ni], 0, 0, 0);
    __syncthreads();
  }

#pragma unroll
  for (int mi = 0; mi < 4; mi++) {
    const int lmb = wr * 64 + mi * 16 + lg * 4;
#pragma unroll
    for (int ni = 0; ni < 4; ni++) {
      const int ln = wc * 64 + ni * 16 + lr;
      const int n = n0 + ln;
      const float bv_ = bo[n];
#pragma unroll
      for (int r = 0; r < 4; r++) {
        const int m = m0 + lmb + r;
        out[m * EMB + n] = acc[mi][ni][r] + bv_;
      }
    }
  }
}

// ---------- launch ----------
extern "C" void kernel_launch(void* const* d_in, const int* in_sizes, int n_in,
                              void* d_out, int out_size, void* d_ws,
                              size_t ws_size, hipStream_t stream) {
  const float* x = (const float*)d_in[0];
  const float* Wq = (const float*)d_in[1];
  const float* bq = (const float*)d_in[2];
  const float* Wk = (const float*)d_in[3];
  const float* bk = (const float*)d_in[4];
  const float* Wv = (const float*)d_in[5];
  const float* bv = (const float*)d_in[6];
  const float* Wo = (const float*)d_in[7];
  const float* bo = (const float*)d_in[8];
  float* out = (float*)d_out;

  char* ws = (char*)d_ws;
  u16* xb = (u16*)ws;                      // 8 MB (reused as AO)
  u16* WqT = (u16*)(ws + (8u << 20));      // 2 MB
  u16* WkT = (u16*)(ws + (10u << 20));     // 2 MB
  u16* WvT = (u16*)(ws + (12u << 20));     // 2 MB
  u16* WoT = (u16*)(ws + (14u << 20));     // 2 MB
  u16* Qb = (u16*)(ws + (16u << 20));      // 8 MB
  u16* Kb = (u16*)(ws + (24u << 20));      // 8 MB
  u16* Vtb = (u16*)(ws + (32u << 20));     // 8 MB (total 40 MB)
  u16* AO = xb;

  k_conv_x<<<2048, 256, 0, stream>>>(x, xb);
  dim3 tg(32, 32, 4);
  k_conv_wT4<<<tg, 256, 0, stream>>>(Wq, Wk, Wv, Wo, WqT, WkT, WvT, WoT);
  k_gemm_qkv<<<dim3(32, 24), 256, 0, stream>>>(xb, WqT, WkT, WvT, bq, bk, bv,
                                               Qb, Kb, Vtb);
  k_attn<<<1024, 256, 0, stream>>>(Qb, Kb, Vtb, AO);
  k_gemm_out<<<dim3(32, 8), 256, 0, stream>>>(AO, WoT, bo, out);
}

// Round 5
// 122.525 us; speedup vs baseline: 2.5270x; 1.5578x over previous
//
#include <hip/hip_runtime.h>

typedef unsigned short u16;
typedef u16 u16x8 __attribute__((ext_vector_type(8)));
typedef __bf16 bf16x8 __attribute__((ext_vector_type(8)));
typedef float f32x4 __attribute__((ext_vector_type(4)));

#define EMB 1024
#define TT 2048
#define BB 2
#define NHEADS 16
#define HD 64
#define MTOT (BB * TT)  // 4096

// ---------- helpers ----------
__device__ __forceinline__ u16 f2bf(float f) {
  unsigned u = __builtin_bit_cast(unsigned, f);
  u += 0x7fffu + ((u >> 16) & 1u);
  return (u16)(u >> 16);
}

__device__ __forceinline__ bf16x8 asbf(u16x8 v) {
  return __builtin_bit_cast(bf16x8, v);
}

__device__ __forceinline__ void gload16(const void* g, void* l) {
  __builtin_amdgcn_global_load_lds(
      (const __attribute__((address_space(1))) void*)g,
      (__attribute__((address_space(3))) void*)l, 16, 0, 0);
}

// ---------- conversion kernels ----------
__global__ __launch_bounds__(256) void k_conv_x(const float* __restrict__ x,
                                                u16* __restrict__ xb) {
  int i = blockIdx.x * 256 + threadIdx.x;  // 8 elems per thread
  float4 a = ((const float4*)x)[i * 2];
  float4 b = ((const float4*)x)[i * 2 + 1];
  u16x8 o;
  o[0] = f2bf(a.x); o[1] = f2bf(a.y); o[2] = f2bf(a.z); o[3] = f2bf(a.w);
  o[4] = f2bf(b.x); o[5] = f2bf(b.y); o[6] = f2bf(b.z); o[7] = f2bf(b.w);
  ((u16x8*)xb)[i] = o;
}

// W[k][n] fp32 -> Wt[n][k] bf16 (LDS-tiled transpose), 4 matrices via grid.z
__global__ __launch_bounds__(256) void k_conv_wT4(
    const float* __restrict__ W0, const float* __restrict__ W1,
    const float* __restrict__ W2, const float* __restrict__ W3,
    u16* __restrict__ T0, u16* __restrict__ T1, u16* __restrict__ T2,
    u16* __restrict__ T3) {
  const int z = blockIdx.z;
  const float* __restrict__ W = (z == 0) ? W0 : (z == 1) ? W1 : (z == 2) ? W2 : W3;
  u16* __restrict__ Wt = (z == 0) ? T0 : (z == 1) ? T1 : (z == 2) ? T2 : T3;
  __shared__ float tile[32][33];
  int bx = blockIdx.x * 32, by = blockIdx.y * 32;
  int tx = threadIdx.x & 31;
  int ty = threadIdx.x >> 5;  // 0..7
#pragma unroll
  for (int r = ty; r < 32; r += 8) tile[r][tx] = W[(by + r) * EMB + bx + tx];
  __syncthreads();
#pragma unroll
  for (int r = ty; r < 32; r += 8)
    Wt[(bx + r) * EMB + by + tx] = f2bf(tile[tx][r]);
}

// ---------- fused QKV GEMM ----------
__global__ __launch_bounds__(256) void k_gemm_qkv(
    const u16* __restrict__ xb, const u16* __restrict__ WqT,
    const u16* __restrict__ WkT, const u16* __restrict__ WvT,
    const float* __restrict__ bq, const float* __restrict__ bk,
    const float* __restrict__ bv, u16* __restrict__ Q, u16* __restrict__ K,
    u16* __restrict__ Vt) {
  __shared__ u16 Al[128 * 32];
  __shared__ u16 Bl[128 * 32];
  const int tid = threadIdx.x;
  const int lane = tid & 63;
  const int w = tid >> 6;
  const int wr = w >> 1, wc = w & 1;
  const int lr = lane & 15, lg = lane >> 4;
  const int m0 = blockIdx.x * 128;
  const int nb = blockIdx.y;           // 0..23
  const int seg = nb >> 3;             // 0=Q 1=K 2=V
  const int n0 = (nb & 7) * 128;
  const u16* __restrict__ Bt = (seg == 0) ? WqT : (seg == 1) ? WkT : WvT;
  const float* __restrict__ bias = (seg == 0) ? bq : (seg == 1) ? bk : bv;

  f32x4 acc[4][4];
#pragma unroll
  for (int i = 0; i < 4; i++)
#pragma unroll
    for (int j = 0; j < 4; j++) acc[i][j] = (f32x4){0.f, 0.f, 0.f, 0.f};

  const int srow = tid >> 2;           // 0..63
  const int scol = (tid & 3) * 8;
  const u16* ga0 = xb + (m0 + srow) * EMB + scol;
  const u16* gb0 = Bt + (n0 + srow) * EMB + scol;
  char* la0 = (char*)Al + w * 1024;    // wave-uniform LDS base
  char* lb0 = (char*)Bl + w * 1024;

  for (int k0 = 0; k0 < EMB; k0 += 32) {
    gload16(ga0 + k0, la0);
    gload16(ga0 + 64 * EMB + k0, la0 + 4096);
    gload16(gb0 + k0, lb0);
    gload16(gb0 + 64 * EMB + k0, lb0 + 4096);
    __syncthreads();
    u16x8 af[4], bfr[4];
#pragma unroll
    for (int mi = 0; mi < 4; mi++)
      af[mi] = *(const u16x8*)&Al[(wr * 64 + mi * 16 + lr) * 32 + lg * 8];
#pragma unroll
    for (int ni = 0; ni < 4; ni++)
      bfr[ni] = *(const u16x8*)&Bl[(wc * 64 + ni * 16 + lr) * 32 + lg * 8];
#pragma unroll
    for (int mi = 0; mi < 4; mi++)
#pragma unroll
      for (int ni = 0; ni < 4; ni++)
        acc[mi][ni] = __builtin_amdgcn_mfma_f32_16x16x32_bf16(
            asbf(af[mi]), asbf(bfr[ni]), acc[mi][ni], 0, 0, 0);
    __syncthreads();
  }

#pragma unroll
  for (int mi = 0; mi < 4; mi++) {
    const int lmb = wr * 64 + mi * 16 + lg * 4;
#pragma unroll
    for (int ni = 0; ni < 4; ni++) {
      const int ln = wc * 64 + ni * 16 + lr;
      const int n = n0 + ln;
      const float bv_ = bias[n];
      const int h = n >> 6, d = n & 63;
#pragma unroll
      for (int r = 0; r < 4; r++) {
        const int m = m0 + lmb + r;
        const int b = m >> 11, t = m & 2047;
        float v = acc[mi][ni][r] + bv_;
        if (seg == 0) {
          v *= 0.125f;  // fold 1/sqrt(D) into Q (exact pow2)
          Q[(((b * NHEADS + h) * TT) + t) * HD + d] = f2bf(v);
        } else if (seg == 1) {
          K[(((b * NHEADS + h) * TT) + t) * HD + d] = f2bf(v);
        } else {
          Vt[(((b * NHEADS + h) * HD) + d) * TT + t] = f2bf(v);
        }
      }
    }
  }
}

// ---------- causal flash attention ----------
// Uniform-work pairing: block (bh, pair) handles q-blocks hi=31-pair (waves
// 0-3) and lo=pair (waves 4-7); every block does exactly 33 tile-computes.
// Grid 32x16 = 512 blocks = exactly 2/CU. K/V tile staged once per block,
// shared by both q-blocks (2-phase double-buffered swizzled LDS).
__global__ __launch_bounds__(512) void k_attn(const u16* __restrict__ Q,
                                              const u16* __restrict__ Kg,
                                              const u16* __restrict__ Vt,
                                              u16* __restrict__ AO) {
  __shared__ u16 Kl[2][64 * 64];   // 8KB x2
  __shared__ u16 Vl[2][64 * 64];   // 8KB x2
  __shared__ u16 Plds[8][16][68];  // per-wave P transpose buffer (padded)
  const int tid = threadIdx.x;
  const int lane = tid & 63;
  const int w = tid >> 6;          // 0..7
  const int lr = lane & 15, lg = lane >> 4;
  const int bh = blockIdx.x;       // 0..31
  const int pair = blockIdx.y;     // 0..15
  const int lo = pair, hi = 31 - pair;
  const int qblk = (w < 4) ? hi : lo;      // this wave's q-block
  const int myend = qblk;                  // last k-tile index for this wave
  const int q0 = qblk * 64 + (w & 3) * 16;
  const u16* __restrict__ Qh = Q + bh * TT * HD;
  const u16* __restrict__ Kh = Kg + bh * TT * HD;
  const u16* __restrict__ Vh = Vt + bh * HD * TT;

  // staging: 512 threads cover a full 64x128B tile; thread t = row t>>3,
  // chunk t&7. Linear LDS dest (wave base w*1024 + lane*16) + pre-swizzled
  // global source chunk sc = c ^ (row&7); reads apply the same XOR.
  const int srow = tid >> 3;               // 0..63
  const int sc = (tid & 7) ^ (srow & 7);

  u16x8 qf[2];
  qf[0] = *(const u16x8*)&Qh[(q0 + lr) * HD + lg * 8];
  qf[1] = *(const u16x8*)&Qh[(q0 + lr) * HD + 32 + lg * 8];

  f32x4 accO[4];
#pragma unroll
  for (int i = 0; i < 4; i++) accO[i] = (f32x4){0.f, 0.f, 0.f, 0.f};
  float mst[4] = {-__builtin_inff(), -__builtin_inff(), -__builtin_inff(),
                  -__builtin_inff()};
  float lsum[4] = {0.f, 0.f, 0.f, 0.f};  // per-lane partials (deferred sum)

  const int nkt = hi + 1;  // block-uniform loop count

  // prologue: stage tile 0 into buf 0 (one gload16 per thread per matrix)
  gload16(Kh + srow * HD + sc * 8, (char*)Kl[0] + w * 1024);
  gload16(Vh + srow * TT + 0 + sc * 8, (char*)Vl[0] + w * 1024);
  __syncthreads();  // drains vmcnt

  for (int kt = 0; kt < nkt; ++kt) {
    const int k0 = kt * 64;
    const int cur = kt & 1;
    if (kt + 1 < nkt) {  // issue next-tile loads BEFORE compute (2-phase)
      const int kn = k0 + 64;
      gload16(Kh + (kn + srow) * HD + sc * 8, (char*)Kl[cur ^ 1] + w * 1024);
      gload16(Vh + srow * TT + kn + sc * 8, (char*)Vl[cur ^ 1] + w * 1024);
    }
    if (kt <= myend) {  // wave-uniform: lo-waves idle past their diagonal
      const char* Kc = (const char*)Kl[cur];
      const char* Vc = (const char*)Vl[cur];

      f32x4 s[4];
#pragma unroll
      for (int n = 0; n < 4; n++) s[n] = (f32x4){0.f, 0.f, 0.f, 0.f};
      __builtin_amdgcn_s_setprio(1);
#pragma unroll
      for (int n = 0; n < 4; n++) {
        const int row = n * 16 + lr;
#pragma unroll
        for (int dh = 0; dh < 2; dh++) {
          const int bo = (dh * 64 + lg * 16) ^ ((row & 7) << 4);
          u16x8 kf = *(const u16x8*)(Kc + row * 128 + bo);
          s[n] = __builtin_amdgcn_mfma_f32_16x16x32_bf16(asbf(qf[dh]),
                                                         asbf(kf), s[n], 0, 0, 0);
        }
      }
      __builtin_amdgcn_s_setprio(0);
      if (kt == myend) {  // diagonal tile: causal mask
#pragma unroll
        for (int n = 0; n < 4; n++)
#pragma unroll
          for (int r = 0; r < 4; r++) {
            int col = k0 + n * 16 + lr, row = q0 + lg * 4 + r;
            if (col > row) s[n][r] = -__builtin_inff();
          }
      }
      // T13 defer-max: skip butterfly+rescale unless max grew by > 8.
      float lmax[4];
#pragma unroll
      for (int r = 0; r < 4; r++)
        lmax[r] = fmaxf(fmaxf(s[0][r], s[1][r]), fmaxf(s[2][r], s[3][r]));
      float g0 = fmaxf(lmax[0] - mst[0], lmax[1] - mst[1]);
      float g1 = fmaxf(lmax[2] - mst[2], lmax[3] - mst[3]);
      if (!__all(fmaxf(g0, g1) <= 8.0f)) {  // rare path (always tile 0)
#pragma unroll
        for (int r = 0; r < 4; r++) {
          float rm = lmax[r];
          rm = fmaxf(rm, __shfl_xor(rm, 1, 16));
          rm = fmaxf(rm, __shfl_xor(rm, 2, 16));
          rm = fmaxf(rm, __shfl_xor(rm, 4, 16));
          rm = fmaxf(rm, __shfl_xor(rm, 8, 16));
          float mnew = fmaxf(mst[r], rm);
          float corr = __expf(mst[r] - mnew);
          lsum[r] *= corr;
          mst[r] = mnew;
#pragma unroll
          for (int dt = 0; dt < 4; dt++) accO[dt][r] *= corr;
        }
      }
#pragma unroll
      for (int r = 0; r < 4; r++) {
        float p0 = __expf(s[0][r] - mst[r]);
        float p1 = __expf(s[1][r] - mst[r]);
        float p2 = __expf(s[2][r] - mst[r]);
        float p3 = __expf(s[3][r] - mst[r]);
        lsum[r] += (p0 + p1) + (p2 + p3);
        const int row = lg * 4 + r;
        Plds[w][row][lr] = f2bf(p0);
        Plds[w][row][16 + lr] = f2bf(p1);
        Plds[w][row][32 + lr] = f2bf(p2);
        Plds[w][row][48 + lr] = f2bf(p3);
      }
      // PV: A = P (16x64) via LDS transpose; B = V rows from swizzled LDS
      u16x8 pa0 = *(const u16x8*)&Plds[w][lr][lg * 8];
      u16x8 pa1 = *(const u16x8*)&Plds[w][lr][32 + lg * 8];
      __builtin_amdgcn_s_setprio(1);
#pragma unroll
      for (int dt = 0; dt < 4; dt++) {
        const int row = dt * 16 + lr;
        const int bo0 = (lg * 16) ^ ((row & 7) << 4);
        const int bo1 = (64 + lg * 16) ^ ((row & 7) << 4);
        u16x8 vf0 = *(const u16x8*)(Vc + row * 128 + bo0);
        u16x8 vf1 = *(const u16x8*)(Vc + row * 128 + bo1);
        accO[dt] = __builtin_amdgcn_mfma_f32_16x16x32_bf16(asbf(pa0),
                                                           asbf(vf0), accO[dt], 0, 0, 0);
        accO[dt] = __builtin_amdgcn_mfma_f32_16x16x32_bf16(asbf(pa1),
                                                           asbf(vf1), accO[dt], 0, 0, 0);
      }
      __builtin_amdgcn_s_setprio(0);
    }
    __syncthreads();  // drains vmcnt: next buf staged; cur free to overwrite
  }
  // final row-sum butterfly + epilogue -> AO [B][T][EMB] bf16
  float rinv[4];
#pragma unroll
  for (int r = 0; r < 4; r++) {
    float t = lsum[r];
    t += __shfl_xor(t, 1, 16);
    t += __shfl_xor(t, 2, 16);
    t += __shfl_xor(t, 4, 16);
    t += __shfl_xor(t, 8, 16);
    rinv[r] = 1.0f / t;
  }
  const int b = bh >> 4, h = bh & 15;
#pragma unroll
  for (int dt = 0; dt < 4; dt++)
#pragma unroll
    for (int r = 0; r < 4; r++) {
      const int row = q0 + lg * 4 + r;
      const int d = h * 64 + dt * 16 + lr;
      AO[(b * TT + row) * EMB + d] = f2bf(accO[dt][r] * rinv[r]);
    }
}

// ---------- output projection GEMM (fp32 out + bias) ----------
__global__ __launch_bounds__(256) void k_gemm_out(const u16* __restrict__ AO,
                                                  const u16* __restrict__ WoT,
                                                  const float* __restrict__ bo,
                                                  float* __restrict__ out) {
  __shared__ u16 Al[128 * 32];
  __shared__ u16 Bl[128 * 32];
  const int tid = threadIdx.x;
  const int lane = tid & 63;
  const int w = tid >> 6;
  const int wr = w >> 1, wc = w & 1;
  const int lr = lane & 15, lg = lane >> 4;
  const int m0 = blockIdx.x * 128;
  const int n0 = blockIdx.y * 128;

  f32x4 acc[4][4];
#pragma unroll
  for (int i = 0; i < 4; i++)
#pragma unroll
    for (int j = 0; j < 4; j++) acc[i][j] = (f32x4){0.f, 0.f, 0.f, 0.f};

  const int srow = tid >> 2;
  const int scol = (tid & 3) * 8;
  const u16* ga0 = AO + (m0 + srow) * EMB + scol;
  const u16* gb0 = WoT + (n0 + srow) * EMB + scol;
  char* la0 = (char*)Al + w * 1024;
  char* lb0 = (char*)Bl + w * 1024;

  for (int k0 = 0; k0 < EMB; k0 += 32) {
    gload16(ga0 + k0, la0);
    gload16(ga0 + 64 * EMB + k0, la0 + 4096);
    gload16(gb0 + k0, lb0);
    gload16(gb0 + 64 * EMB + k0, lb0 + 4096);
    __syncthreads();
    u16x8 af[4], bfr[4];
#pragma unroll
    for (int mi = 0; mi < 4; mi++)
      af[mi] = *(const u16x8*)&Al[(wr * 64 + mi * 16 + lr) * 32 + lg * 8];
#pragma unroll
    for (int ni = 0; ni < 4; ni++)
      bfr[ni] = *(const u16x8*)&Bl[(wc * 64 + ni * 16 + lr) * 32 + lg * 8];
#pragma unroll
    for (int mi = 0; mi < 4; mi++)
#pragma unroll
      for (int ni = 0; ni < 4; ni++)
        acc[mi][ni] = __builtin_amdgcn_mfma_f32_16x16x32_bf16(
            asbf(af[mi]), asbf(bfr[ni]), acc[mi][ni], 0, 0, 0);
    __syncthreads();
  }

#pragma unroll
  for (int mi = 0; mi < 4; mi++) {
    const int lmb = wr * 64 + mi * 16 + lg * 4;
#pragma unroll
    for (int ni = 0; ni < 4; ni++) {
      const int ln = wc * 64 + ni * 16 + lr;
      const int n = n0 + ln;
      const float bv_ = bo[n];
#pragma unroll
      for (int r = 0; r < 4; r++) {
        const int m = m0 + lmb + r;
        out[m * EMB + n] = acc[mi][ni][r] + bv_;
      }
    }
  }
}

// ---------- launch ----------
extern "C" void kernel_launch(void* const* d_in, const int* in_sizes, int n_in,
                              void* d_out, int out_size, void* d_ws,
                              size_t ws_size, hipStream_t stream) {
  const float* x = (const float*)d_in[0];
  const float* Wq = (const float*)d_in[1];
  const float* bq = (const float*)d_in[2];
  const float* Wk = (const float*)d_in[3];
  const float* bk = (const float*)d_in[4];
  const float* Wv = (const float*)d_in[5];
  const float* bv = (const float*)d_in[6];
  const float* Wo = (const float*)d_in[7];
  const float* bo = (const float*)d_in[8];
  float* out = (float*)d_out;

  char* ws = (char*)d_ws;
  u16* xb = (u16*)ws;                      // 8 MB (reused as AO)
  u16* WqT = (u16*)(ws + (8u << 20));      // 2 MB
  u16* WkT = (u16*)(ws + (10u << 20));     // 2 MB
  u16* WvT = (u16*)(ws + (12u << 20));     // 2 MB
  u16* WoT = (u16*)(ws + (14u << 20));     // 2 MB
  u16* Qb = (u16*)(ws + (16u << 20));      // 8 MB
  u16* Kb = (u16*)(ws + (24u << 20));      // 8 MB
  u16* Vtb = (u16*)(ws + (32u << 20));     // 8 MB (total 40 MB)
  u16* AO = xb;

  k_conv_x<<<2048, 256, 0, stream>>>(x, xb);
  dim3 tg(32, 32, 4);
  k_conv_wT4<<<tg, 256, 0, stream>>>(Wq, Wk, Wv, Wo, WqT, WkT, WvT, WoT);
  k_gemm_qkv<<<dim3(32, 24), 256, 0, stream>>>(xb, WqT, WkT, WvT, bq, bk, bv,
                                               Qb, Kb, Vtb);
  k_attn<<<dim3(32, 16), 512, 0, stream>>>(Qb, Kb, Vtb, AO);
  k_gemm_out<<<dim3(32, 8), 256, 0, stream>>>(AO, WoT, bo, out);
}